// Round 9
// baseline (286.906 us; speedup 1.0000x reference)
//
#include <hip/hip_runtime.h>
#include <stdint.h>

#define B_ 8
#define N_ 2048
#define D_ 120
#define DP 128          // D padded to 128 (k-dim of MFMA)
#define QB 32           // q rows per attention block
#define MT 32           // m-tile (k/v rows per step)
#define NT (N_ / MT)    // 64 steps

typedef __attribute__((ext_vector_type(8))) short short8;
typedef __attribute__((ext_vector_type(4))) float f32x4;
typedef __attribute__((ext_vector_type(4))) float float4v;
typedef unsigned short u16;
typedef unsigned int u32;

__device__ __forceinline__ u16 f2bf(float f){
    union { float f; uint32_t u; } v; v.f = f;
    uint32_t u = v.u;
    return (u16)((u + 0x7fffu + ((u >> 16) & 1u)) >> 16);
}
__device__ __forceinline__ float bf2f(u16 h){
    union { uint32_t u; float f; } v; v.u = ((uint32_t)h) << 16; return v.f;
}
__device__ __forceinline__ f32x4 mfma16(short8 a, short8 b, f32x4 c){
    return __builtin_amdgcn_mfma_f32_16x16x32_bf16(a, b, c, 0, 0, 0);
}

// LDS-only barrier: drain LDS ops, do NOT drain vmcnt.
__device__ __forceinline__ void bar_lds(){
    asm volatile("s_waitcnt lgkmcnt(0)\n\ts_barrier" ::: "memory");
}

// ---------------------------------------------------------------------------
// Kernel 0: transpose + split weights (bf16 hi/lo), zero-padded to 128x128.
// ---------------------------------------------------------------------------
__global__ void wprep(const float* __restrict__ Wq, const float* __restrict__ Wk,
                      const float* __restrict__ Wv,
                      u16* __restrict__ Wth, u16* __restrict__ Wtl){
    int p = blockIdx.x;
    const float* W = (p == 0) ? Wq : (p == 1 ? Wk : Wv);
    float scale = (p == 0) ? 0.09128709291752768f : 1.0f;  // 1/sqrt(120)
    for (int idx = threadIdx.x; idx < DP * DP; idx += blockDim.x){
        int c = idx & (DP - 1);
        int d = idx >> 7;
        float w = (c < D_ && d < D_) ? W[d * D_ + c] * scale : 0.f;
        u16 hi = f2bf(w);
        Wth[p * DP * DP + c * DP + d] = hi;
        Wtl[p * DP * DP + c * DP + d] = f2bf(w - bf2f(hi));
    }
}

// ---------------------------------------------------------------------------
// Kernel 1: projections. W (hi+lo) staged in swizzled LDS; V written
// tile-major [b][t][e][32] via LDS transpose (coalesced stores).
// ---------------------------------------------------------------------------
__global__ __launch_bounds__(256, 2)
void proj_kernel(const float* __restrict__ x1, const float* __restrict__ x2,
                 const u16* __restrict__ Wth, const u16* __restrict__ Wtl,
                 u16* __restrict__ Qh, u16* __restrict__ Ql,
                 u16* __restrict__ Kh, u16* __restrict__ Kl,
                 u16* __restrict__ Vt){
    __shared__ short8 smem8[4096];          // 64 KB: WH[2048] | WL[2048]
    short8* WHs = smem8;
    short8* WLs = smem8 + 2048;
    u16* vtl = (u16*)smem8;                 // reused after compute: [128][64]

    int p    = blockIdx.y;
    const float* x = (p == 0) ? x1 : x2;
    int tid  = threadIdx.x;
    int wave = tid >> 6, lane = tid & 63;
    int g = lane >> 4, ln = lane & 15;
    long arow = (long)blockIdx.x * 64 + wave * 16 + ln;

    const u16* wh = Wth + p * DP * DP;
    const u16* wl = Wtl + p * DP * DP;
    #pragma unroll
    for (int j = 0; j < 8; ++j){
        int u = tid + j * 256;
        int row = u >> 4, cu = u & 15;
        int slot = row * 16 + (cu ^ (row & 7));
        WHs[slot] = *(const short8*)(wh + (long)u * 8);
        WLs[slot] = *(const short8*)(wl + (long)u * 8);
    }

    short8 ah[4], al[4];
    #pragma unroll
    for (int ks = 0; ks < 4; ++ks){
        int d0 = ks * 32 + g * 8;
        float xv[8];
        if (d0 < D_){
            float4v v0 = *(const float4v*)(x + arow * D_ + d0);
            float4v v1 = *(const float4v*)(x + arow * D_ + d0 + 4);
            xv[0]=v0[0]; xv[1]=v0[1]; xv[2]=v0[2]; xv[3]=v0[3];
            xv[4]=v1[0]; xv[5]=v1[1]; xv[6]=v1[2]; xv[7]=v1[3];
        } else {
            #pragma unroll
            for (int j = 0; j < 8; ++j) xv[j] = 0.f;
        }
        short8 h, l;
        #pragma unroll
        for (int j = 0; j < 8; ++j){
            u16 hb = f2bf(xv[j]);
            h[j] = (short)hb;
            l[j] = (short)f2bf(xv[j] - bf2f(hb));
        }
        ah[ks] = h; al[ks] = l;
    }
    __syncthreads();

    f32x4 acc[8];
    #pragma unroll
    for (int cf = 0; cf < 8; ++cf){
        f32x4 s0 = {0.f,0.f,0.f,0.f}, s1 = {0.f,0.f,0.f,0.f}, s2 = {0.f,0.f,0.f,0.f};
        int rbase = (cf * 16 + ln) * 16;
        #pragma unroll
        for (int ks = 0; ks < 4; ++ks){
            int cu = (ks * 4 + g) ^ (ln & 7);
            short8 bh = WHs[rbase + cu];
            short8 bl = WLs[rbase + cu];
            s0 = mfma16(ah[ks], bh, s0);
            s1 = mfma16(al[ks], bh, s1);
            s2 = mfma16(ah[ks], bl, s2);
        }
        acc[cf] = s0 + s1 + s2;
    }

    if (p < 2){
        #pragma unroll
        for (int cf = 0; cf < 8; ++cf){
            #pragma unroll
            for (int i = 0; i < 4; ++i){
                long orow = (long)blockIdx.x * 64 + wave * 16 + g * 4 + i;
                int  c    = cf * 16 + ln;
                float v   = acc[cf][i];
                u16 hb = f2bf(v);
                if (p == 0){
                    Qh[orow * DP + c] = hb;
                    Ql[orow * DP + c] = f2bf(v - bf2f(hb));
                } else {
                    Kh[orow * DP + c] = hb;
                    Kl[orow * DP + c] = f2bf(v - bf2f(hb));
                }
            }
        }
    } else {
        __syncthreads();
        #pragma unroll
        for (int cf = 0; cf < 8; ++cf){
            #pragma unroll
            for (int i = 0; i < 4; ++i){
                int c    = cf * 16 + ln;
                int lrow = wave * 16 + g * 4 + i;
                vtl[c * 64 + lrow] = f2bf(acc[cf][i]);
            }
        }
        __syncthreads();
        int c = tid >> 1, half = tid & 1;
        long n0 = ((long)blockIdx.x * 64) & 2047;
        long bb = ((long)blockIdx.x * 64) >> 11;
        long tbase = ((bb * 64 + (n0 >> 5) + half) * 128 + c) * 32;
        #pragma unroll
        for (int j = 0; j < 4; ++j){
            short8 v = *(const short8*)&vtl[c * 64 + half * 32 + j * 8];
            *(short8*)(Vt + tbase + j * 8) = v;
        }
    }
}

// ---------------------------------------------------------------------------
// Kernel 2: fused attention, two-phase with S stored in the attnw buffer.
// Pass A: QK^T once, online (max,l), store masked raw S (f32) into attnw.
// Pass B: stream S back (prefetched), P = exp(S-M)*invL, write P in-place
// (coalesced), PV from LDS P-tile + V-tile. No QK^T recompute, no K LDS in
// pass B. Mask is read (raw ints, 2-deep prefetch) only in pass A, so the
// separate maskprep kernel is eliminated.
// ---------------------------------------------------------------------------
#define ISSUE_K(P, T) do{ long gb_ = (long)(T) * MT * DP;                         \
    P##h0 = *(const short8*)(Kbh + gb_ + (long)tid * 8);                          \
    P##h1 = *(const short8*)(Kbh + gb_ + (long)(tid + 256) * 8);                  \
    P##l0 = *(const short8*)(Kbl + gb_ + (long)tid * 8);                          \
    P##l1 = *(const short8*)(Kbl + gb_ + (long)(tid + 256) * 8); }while(0)

#define WRITE_K(BUF, P) do{                                                       \
    KsH[BUF][slot0] = P##h0; KsH[BUF][slot1] = P##h1;                             \
    KsL[BUF][slot0] = P##l0; KsL[BUF][slot1] = P##l1; }while(0)

#define ISSUE_V(P, T) do{ const u16* vt_ = Vb + (long)(T) * 4096;                 \
    P##0 = *(const short8*)(vt_ + (long)tid * 8);                                 \
    P##1 = *(const short8*)(vt_ + (long)(tid + 256) * 8); }while(0)

#define WRITE_V(BUF, P) do{ Vs[BUF][vslot0] = P##0; Vs[BUF][vslot1] = P##1; }while(0)

#define ISSUE_M(P, T) do{                                                         \
    P##0 = mask[ofs_[0] + (long)(T) * MT];                                        \
    P##1 = mask[ofs_[1] + (long)(T) * MT];                                        \
    P##2 = mask[ofs_[2] + (long)(T) * MT];                                        \
    P##3 = mask[ofs_[3] + (long)(T) * MT]; }while(0)

#define COMPUTE_S(CB, SD) do{                                                     \
    f32x4 s0_ = {0.f,0.f,0.f,0.f}, s1_ = s0_, s2_ = s0_;                          \
    __builtin_amdgcn_s_setprio(1);                                                \
    _Pragma("unroll") for (int ks_ = 0; ks_ < 4; ++ks_){                          \
        int cu_ = (ks_ * 4 + g) ^ swz;                                            \
        short8 bh_ = KsH[CB][mrow * 16 + cu_];                                    \
        short8 bl_ = KsL[CB][mrow * 16 + cu_];                                    \
        s0_ = mfma16(ah[ks_], bh_, s0_);                                          \
        s1_ = mfma16(al[ks_], bh_, s1_);                                          \
        s2_ = mfma16(ah[ks_], bl_, s2_); }                                        \
    __builtin_amdgcn_s_setprio(0);                                                \
    SD = s0_ + s1_ + s2_; }while(0)

// masked-S store + lazy online max/sum (sentinel -3e38 for masked)
#define AONLINE(MV, S, T) do{ int mv_[4] = {MV##0, MV##1, MV##2, MV##3};          \
    _Pragma("unroll") for (int i = 0; i < 4; ++i){                                \
        float sv_ = mv_[i] ? (S)[i] : -3.0e38f;                                   \
        attnw[ofs_[i] + (long)(T) * MT] = sv_;                                    \
        if (__any(sv_ > mx[i])){                                                  \
            float nm_ = fmaxf(mx[i], sv_);                                        \
            ls[i] *= __expf(mx[i] - nm_); mx[i] = nm_;                            \
        }                                                                         \
        ls[i] += __expf(sv_ - mx[i]); } }while(0)

// pass-B: consume prefetched S, produce normalized P -> attnw (in-place) + Ps
#define PB_STEP(PARITY, SP, TT) do{                                               \
    f32x4 S4_ = SP;                                                               \
    if ((TT) + 2 < NT) SP = *(const f32x4*)(attnw + sofs + (long)((TT) + 2) * MT);\
    f32x4 P4_;                                                                    \
    _Pragma("unroll") for (int j = 0; j < 4; ++j)                                 \
        P4_[j] = __expf(S4_[j] - Ms) * Is;                                        \
    *(f32x4*)(attnw + sofs + (long)(TT) * MT) = P4_;                              \
    *(f32x4*)&Ps[PARITY][pslot] = P4_; }while(0)

#define PV_STEP(PB, VBUF) do{                                                     \
    int prow_ = rt * 16 + ln, sx_ = (prow_ & 7) << 2;                             \
    f32x4 pq0_ = *(const f32x4*)&Ps[PB][prow_ * 32 + ((g * 8) ^ sx_)];            \
    f32x4 pq1_ = *(const f32x4*)&Ps[PB][prow_ * 32 + (((g * 8) + 4) ^ sx_)];      \
    union { u32 w[4]; short8 s8; } pu_;                                           \
    asm("v_cvt_pk_bf16_f32 %0, %1, %2" : "=v"(pu_.w[0]) : "v"(pq0_[0]), "v"(pq0_[1])); \
    asm("v_cvt_pk_bf16_f32 %0, %1, %2" : "=v"(pu_.w[1]) : "v"(pq0_[2]), "v"(pq0_[3])); \
    asm("v_cvt_pk_bf16_f32 %0, %1, %2" : "=v"(pu_.w[2]) : "v"(pq1_[0]), "v"(pq1_[1])); \
    asm("v_cvt_pk_bf16_f32 %0, %1, %2" : "=v"(pu_.w[3]) : "v"(pq1_[2]), "v"(pq1_[3])); \
    short8 pa_ = pu_.s8;                                                          \
    __builtin_amdgcn_s_setprio(1);                                                \
    _Pragma("unroll") for (int ef_ = 0; ef_ < 4; ++ef_){                          \
        int e_ = wc * 64 + ef_ * 16 + ln;                                         \
        short8 vb_ = Vs[VBUF][e_ * 4 + (g ^ ((e_ >> 1) & 3))];                    \
        acc[ef_] = mfma16(pa_, vb_, acc[ef_]); }                                  \
    __builtin_amdgcn_s_setprio(0); }while(0)

__global__ __launch_bounds__(256, 2)
void attn_kernel(const u16* __restrict__ Qh, const u16* __restrict__ Ql,
                 const u16* __restrict__ Kh, const u16* __restrict__ Kl,
                 const u16* __restrict__ Vt, const int* __restrict__ mask,
                 float* __restrict__ outp, float* __restrict__ attnw){
    __shared__ short8 KsH[2][512];     // [buf][32 rows x 16 units] swizzled
    __shared__ short8 KsL[2][512];
    __shared__ short8 Vs [2][512];     // [buf][128 e x 4 units] swizzled
    __shared__ float  Ps [2][QB * MT]; // [buf] P tile, col ^ ((row&7)<<2)
    __shared__ float  redM[2][QB];
    __shared__ float  redL[2][QB];
    __shared__ float  smax[QB];
    __shared__ float  sinv[QB];

    int lin = blockIdx.x;
    int b   = lin & 7;                  // batch == XCD (round-robin dispatch)
    int q0  = (lin >> 3) * QB;
    int tid = threadIdx.x;
    int w   = tid >> 6, lane = tid & 63;
    int rt  = w & 1, wc = w >> 1;
    int g   = lane >> 4, ln = lane & 15;

    long rowbase = (long)b * N_ + q0;
    const u16* Kbh = Kh + (long)b * N_ * DP;
    const u16* Kbl = Kl + (long)b * N_ * DP;
    const u16* Vb  = Vt + ((long)b * 64) * 4096;   // tile-major: +t*4096

    // Q A-fragments
    short8 ah[4], al[4];
    {
        const u16* qh = Qh + (rowbase + rt * 16 + ln) * DP;
        const u16* ql = Ql + (rowbase + rt * 16 + ln) * DP;
        #pragma unroll
        for (int ks = 0; ks < 4; ++ks){
            ah[ks] = *(const short8*)(qh + ks * 32 + g * 8);
            al[ks] = *(const short8*)(ql + ks * 32 + g * 8);
        }
    }

    int mrow  = wc * 16 + ln;
    int swz   = ln & 7;
    // element offsets shared by mask (int) and attnw (f32): same geometry
    long ofs_[4];
    #pragma unroll
    for (int i = 0; i < 4; ++i)
        ofs_[i] = (rowbase + rt * 16 + g * 4 + i) * N_ + wc * 16 + ln;

    int r0 = tid >> 4,          c0 = tid & 15;
    int slot0 = r0 * 16 + (c0 ^ (r0 & 7));
    int r1 = (tid + 256) >> 4,  c1 = tid & 15;
    int slot1 = r1 * 16 + (c1 ^ (r1 & 7));
    int e0 = tid >> 2,          m0 = tid & 3;
    int vslot0 = e0 * 4 + (m0 ^ ((e0 >> 1) & 3));
    int e1 = (tid + 256) >> 2;
    int vslot1 = e1 * 4 + (m0 ^ ((e1 >> 1) & 3));

    // prefetch register sets (statically named — rule #20)
    short8 kAh0, kAh1, kAl0, kAl1;
    short8 kBh0, kBh1, kBl0, kBl1;
    short8 vA0, vA1, vB0, vB1;
    int mA0, mA1, mA2, mA3, mB0, mB1, mB2, mB3;

    // ================= PASS A: QK^T + online max/sum + S store =============
    float mx[4], ls[4];
    #pragma unroll
    for (int i = 0; i < 4; ++i){ mx[i] = -1e30f; ls[i] = 0.f; }

    {   // prologue: direct-stage K0, prefetch K1/K2, mask 0/1
        short8 h0 = *(const short8*)(Kbh + (long)tid * 8);
        short8 h1 = *(const short8*)(Kbh + (long)(tid + 256) * 8);
        short8 l0 = *(const short8*)(Kbl + (long)tid * 8);
        short8 l1 = *(const short8*)(Kbl + (long)(tid + 256) * 8);
        ISSUE_K(kA, 1);
        ISSUE_K(kB, 2);
        ISSUE_M(mA, 0);
        ISSUE_M(mB, 1);
        KsH[0][slot0] = h0; KsH[0][slot1] = h1;
        KsL[0][slot0] = l0; KsL[0][slot1] = l1;
        bar_lds();
    }
    for (int t = 0; t < NT; t += 2){
        f32x4 s;
        COMPUTE_S(0, s);
        AONLINE(mA, s, t);
        WRITE_K(1, kA);                       // tile t+1 (issued >=2 iters ago)
        if (t + 3 < NT) ISSUE_K(kA, t + 3);
        if (t + 2 < NT) ISSUE_M(mA, t + 2);
        bar_lds();

        COMPUTE_S(1, s);
        AONLINE(mB, s, t + 1);
        if (t + 2 < NT) WRITE_K(0, kB);       // tile t+2
        if (t + 4 < NT) ISSUE_K(kB, t + 4);
        if (t + 3 < NT) ISSUE_M(mB, t + 3);
        bar_lds();
    }

    // merge across the 16 ln lanes
    #pragma unroll
    for (int i = 0; i < 4; ++i){
        #pragma unroll
        for (int sft = 1; sft < 16; sft <<= 1){
            float om = __shfl_xor(mx[i], sft, 64);
            float ol = __shfl_xor(ls[i], sft, 64);
            float nm = fmaxf(mx[i], om);
            ls[i] = ls[i] * __expf(mx[i] - nm) + ol * __expf(om - nm);
            mx[i] = nm;
        }
    }
    if (ln == 0){
        #pragma unroll
        for (int i = 0; i < 4; ++i){
            redM[wc][rt * 16 + g * 4 + i] = mx[i];
            redL[wc][rt * 16 + g * 4 + i] = ls[i];
        }
    }
    __syncthreads();
    if (tid < QB){
        float m0_ = redM[0][tid], m1_ = redM[1][tid];
        float M  = fmaxf(m0_, m1_);
        float L  = redL[0][tid] * __expf(m0_ - M) + redL[1][tid] * __expf(m1_ - M);
        smax[tid] = M;
        sinv[tid] = 1.f / L;
    }
    // ensure all pass-A S stores complete & visible before pass-B loads
    __threadfence();
    __syncthreads();

    // ================= PASS B: stream S -> P + PV =================
    f32x4 acc[4];
    #pragma unroll
    for (int e = 0; e < 4; ++e) acc[e] = (f32x4){0.f, 0.f, 0.f, 0.f};

    int srow = tid >> 3, scol = (tid & 7) * 4;
    long sofs = (rowbase + srow) * N_ + scol;
    int pslot = srow * 32 + (scol ^ ((srow & 7) << 2));
    float Ms = smax[srow], Is = sinv[srow];

    f32x4 sA, sB;
    {   // prologue: prefetch S0/S1, V0/V1
        sA = *(const f32x4*)(attnw + sofs);
        sB = *(const f32x4*)(attnw + sofs + MT);
        ISSUE_V(vA, 0);
        ISSUE_V(vB, 1);
    }
    for (int t = 0; t < NT; t += 2){
        // even sub-iter: tile t
        PB_STEP(0, sA, t);
        WRITE_V(0, vA);
        if (t + 2 < NT) ISSUE_V(vA, t + 2);
        if (t > 0) PV_STEP(1, 1);             // PV for tile t-1
        bar_lds();

        // odd sub-iter: tile t+1
        PB_STEP(1, sB, t + 1);
        WRITE_V(1, vB);
        if (t + 3 < NT) ISSUE_V(vB, t + 3);
        PV_STEP(0, 0);                        // PV for tile t
        bar_lds();
    }
    PV_STEP(1, 1);                            // epilogue: tile NT-1

    // ---- output store ----
    #pragma unroll
    for (int ef = 0; ef < 4; ++ef){
        #pragma unroll
        for (int i = 0; i < 4; ++i){
            int col = wc * 64 + ef * 16 + ln;
            if (col < D_)
                outp[(rowbase + rt * 16 + g * 4 + i) * D_ + col] = acc[ef][i];
        }
    }
}

// ---------------------------------------------------------------------------
extern "C" void kernel_launch(void* const* d_in, const int* in_sizes, int n_in,
                              void* d_out, int out_size, void* d_ws, size_t ws_size,
                              hipStream_t stream){
    const float* x1   = (const float*)d_in[0];
    const float* x2   = (const float*)d_in[1];
    const int*   mask = (const int*)d_in[2];
    const float* Wq   = (const float*)d_in[3];
    const float* Wk   = (const float*)d_in[4];
    const float* Wv   = (const float*)d_in[5];

    float* outp  = (float*)d_out;
    float* attnw = outp + (size_t)B_ * N_ * D_;   // outputs concatenated flat

    const size_t TEN = (size_t)B_ * N_ * DP;      // 2,097,152
    u16* Qh   = (u16*)d_ws;
    u16* Ql   = Qh + TEN;
    u16* Kh   = Ql + TEN;
    u16* Kl   = Kh + TEN;
    u16* Vt   = Kl + TEN;                         // tile-major [B][64][128][32]
    u16* Wth  = Vt + TEN;
    u16* Wtl  = Wth + (size_t)3 * DP * DP;

    hipLaunchKernelGGL(wprep, dim3(3), dim3(256), 0, stream, Wq, Wk, Wv, Wth, Wtl);
    hipLaunchKernelGGL(proj_kernel, dim3((B_ * N_) / 64, 3), dim3(256), 0, stream,
                       x1, x2, Wth, Wtl, Qh, Ql, Kh, Kl, Vt);
    hipLaunchKernelGGL(attn_kernel, dim3((B_ * N_) / QB), dim3(256), 0, stream,
                       Qh, Ql, Kh, Kl, Vt, mask, outp, attnw);
}

// Round 10
// 269.981 us; speedup vs baseline: 1.0627x; 1.0627x over previous
//
#include <hip/hip_runtime.h>
#include <stdint.h>

#define B_ 8
#define N_ 2048
#define D_ 120
#define DP 128          // D padded to 128 (k-dim of MFMA)
#define QB 32           // q rows per attention block
#define MT 32           // m-tile (k/v rows per step)
#define NT2 32          // tiles per m-half (1024/32)

typedef __attribute__((ext_vector_type(8))) short short8;
typedef __attribute__((ext_vector_type(4))) float f32x4;
typedef __attribute__((ext_vector_type(4))) float float4v;
typedef __attribute__((ext_vector_type(2))) unsigned int u32x2;
typedef unsigned short u16;
typedef unsigned int u32;

__device__ __forceinline__ u16 f2bf(float f){
    union { float f; uint32_t u; } v; v.f = f;
    uint32_t u = v.u;
    return (u16)((u + 0x7fffu + ((u >> 16) & 1u)) >> 16);
}
__device__ __forceinline__ float bf2f(u16 h){
    union { uint32_t u; float f; } v; v.u = ((uint32_t)h) << 16; return v.f;
}
__device__ __forceinline__ f32x4 mfma16(short8 a, short8 b, f32x4 c){
    return __builtin_amdgcn_mfma_f32_16x16x32_bf16(a, b, c, 0, 0, 0);
}
// LDS-only barrier: drain LDS ops, not vmcnt.
__device__ __forceinline__ void bar_lds(){
    asm volatile("s_waitcnt lgkmcnt(0)\n\ts_barrier" ::: "memory");
}

// ---------------------------------------------------------------------------
// Kernel 0: transpose + split weights (bf16 hi/lo), zero-padded to 128x128.
// Wq scale = log2(e)/sqrt(120) -> scores live in the exp2 domain.
// ---------------------------------------------------------------------------
__global__ void wprep(const float* __restrict__ Wq, const float* __restrict__ Wk,
                      const float* __restrict__ Wv,
                      u16* __restrict__ Wth, u16* __restrict__ Wtl){
    int p = blockIdx.x;
    const float* W = (p == 0) ? Wq : (p == 1 ? Wk : Wv);
    float scale = (p == 0) ? 0.13169943749474f : 1.0f;   // log2e/sqrt(120)
    for (int idx = threadIdx.x; idx < DP * DP; idx += blockDim.x){
        int c = idx & (DP - 1);
        int d = idx >> 7;
        float w = (c < D_ && d < D_) ? W[d * D_ + c] * scale : 0.f;
        u16 hi = f2bf(w);
        Wth[p * DP * DP + c * DP + d] = hi;
        Wtl[p * DP * DP + c * DP + d] = f2bf(w - bf2f(hi));
    }
}

// ---------------------------------------------------------------------------
// Kernel 1: FUSED projections + mask->bitmask.
// lin <  768 : proj partition (p = lin>>8, bx = lin&255)
// lin >= 768 : maskprep partition (4096 blocks, 1 row per wave)
// ---------------------------------------------------------------------------
__global__ __launch_bounds__(256, 2)
void projmask_kernel(const float* __restrict__ x1, const float* __restrict__ x2,
                     const int* __restrict__ mask,
                     const u16* __restrict__ Wth, const u16* __restrict__ Wtl,
                     u16* __restrict__ Qh, u16* __restrict__ Ql,
                     u16* __restrict__ Kh, u16* __restrict__ Kl,
                     u16* __restrict__ Vt, u32* __restrict__ bits){
    __shared__ short8 smem8[4096];          // 64 KB: WH[2048] | WL[2048]
    int lin = blockIdx.x;
    int tid = threadIdx.x;

    if (lin >= 768){                        // ---- mask partition ----
        int mb   = lin - 768;
        int wid  = (mb * 256 + tid) >> 6;   // row index
        int lane = tid & 63;
        long base = (long)wid * N_;
        u32 myw = 0;
        #pragma unroll
        for (int it = 0; it < 32; ++it){
            int v = mask[base + it * 64 + lane];
            unsigned long long bb = __ballot(v != 0);
            if ((lane >> 1) == it)
                myw = (lane & 1) ? (u32)(bb >> 32) : (u32)bb;
        }
        bits[((long)wid << 6) + lane] = myw;
        return;
    }

    // ---- proj partition ----
    short8* WHs = smem8;
    short8* WLs = smem8 + 2048;
    u16* vtl = (u16*)smem8;                 // reused after compute: [128][64]

    int p  = lin >> 8;
    int bx = lin & 255;
    const float* x = (p == 0) ? x1 : x2;
    int wave = tid >> 6, lane = tid & 63;
    int g = lane >> 4, ln = lane & 15;
    long arow = (long)bx * 64 + wave * 16 + ln;

    const u16* wh = Wth + p * DP * DP;
    const u16* wl = Wtl + p * DP * DP;
    #pragma unroll
    for (int j = 0; j < 8; ++j){
        int u = tid + j * 256;
        int row = u >> 4, cu = u & 15;
        int slot = row * 16 + (cu ^ (row & 7));
        WHs[slot] = *(const short8*)(wh + (long)u * 8);
        WLs[slot] = *(const short8*)(wl + (long)u * 8);
    }

    short8 ah[4], al[4];
    #pragma unroll
    for (int ks = 0; ks < 4; ++ks){
        int d0 = ks * 32 + g * 8;
        float xv[8];
        if (d0 < D_){
            float4v v0 = *(const float4v*)(x + arow * D_ + d0);
            float4v v1 = *(const float4v*)(x + arow * D_ + d0 + 4);
            xv[0]=v0[0]; xv[1]=v0[1]; xv[2]=v0[2]; xv[3]=v0[3];
            xv[4]=v1[0]; xv[5]=v1[1]; xv[6]=v1[2]; xv[7]=v1[3];
        } else {
            #pragma unroll
            for (int j = 0; j < 8; ++j) xv[j] = 0.f;
        }
        short8 h, l;
        #pragma unroll
        for (int j = 0; j < 8; ++j){
            u16 hb = f2bf(xv[j]);
            h[j] = (short)hb;
            l[j] = (short)f2bf(xv[j] - bf2f(hb));
        }
        ah[ks] = h; al[ks] = l;
    }
    __syncthreads();

    f32x4 acc[8];
    #pragma unroll
    for (int cf = 0; cf < 8; ++cf){
        f32x4 s0 = {0.f,0.f,0.f,0.f}, s1 = {0.f,0.f,0.f,0.f}, s2 = {0.f,0.f,0.f,0.f};
        int rbase = (cf * 16 + ln) * 16;
        #pragma unroll
        for (int ks = 0; ks < 4; ++ks){
            int cu = (ks * 4 + g) ^ (ln & 7);
            short8 bh = WHs[rbase + cu];
            short8 bl = WLs[rbase + cu];
            s0 = mfma16(ah[ks], bh, s0);
            s1 = mfma16(al[ks], bh, s1);
            s2 = mfma16(ah[ks], bl, s2);
        }
        acc[cf] = s0 + s1 + s2;
    }

    if (p < 2){
        #pragma unroll
        for (int cf = 0; cf < 8; ++cf){
            #pragma unroll
            for (int i = 0; i < 4; ++i){
                long orow = (long)bx * 64 + wave * 16 + g * 4 + i;
                int  c    = cf * 16 + ln;
                float v   = acc[cf][i];
                u16 hb = f2bf(v);
                if (p == 0){
                    Qh[orow * DP + c] = hb;
                    Ql[orow * DP + c] = f2bf(v - bf2f(hb));
                } else {
                    Kh[orow * DP + c] = hb;
                    Kl[orow * DP + c] = f2bf(v - bf2f(hb));
                }
            }
        }
    } else {
        __syncthreads();
        #pragma unroll
        for (int cf = 0; cf < 8; ++cf){
            #pragma unroll
            for (int i = 0; i < 4; ++i){
                int c    = cf * 16 + ln;
                int lrow = wave * 16 + g * 4 + i;
                vtl[c * 64 + lrow] = f2bf(acc[cf][i]);
            }
        }
        __syncthreads();
        int c = tid >> 1, half = tid & 1;
        long n0 = ((long)bx * 64) & 2047;
        long bb = ((long)bx * 64) >> 11;
        long tbase = ((bb * 64 + (n0 >> 5) + half) * 128 + c) * 32;
        #pragma unroll
        for (int j = 0; j < 4; ++j){
            short8 v = *(const short8*)&vtl[c * 64 + half * 32 + j * 8];
            *(short8*)(Vt + tbase + j * 8) = v;
        }
    }
}

// ---------------------------------------------------------------------------
// shared macros (attn)
// ---------------------------------------------------------------------------
#define ISSUE_K2(P, T) do{ long gb_ = (long)(T) * MT * DP;                        \
    P##h0 = *(const short8*)(Kbh + gb_ + (long)tid * 8);                          \
    P##h1 = *(const short8*)(Kbh + gb_ + (long)(tid + 256) * 8);                  \
    P##l0 = *(const short8*)(Kbl + gb_ + (long)tid * 8);                          \
    P##l1 = *(const short8*)(Kbl + gb_ + (long)(tid + 256) * 8); }while(0)

// ---------------------------------------------------------------------------
// Kernel 2a: pass A — QK^T + online (max, l) over ONE m-half.
// grid 1024 (qb 0..511 x half), LDS 33 KB -> 4 blocks/CU (16 waves).
// ---------------------------------------------------------------------------
__global__ __launch_bounds__(256, 4)
void attnA_kernel(const u16* __restrict__ Qh, const u16* __restrict__ Ql,
                  const u16* __restrict__ Kh, const u16* __restrict__ Kl,
                  const u32* __restrict__ bits,
                  float* __restrict__ Mpart, float* __restrict__ Lpart){
    __shared__ short8 KsH[2][512];
    __shared__ short8 KsL[2][512];
    __shared__ float  redM[2][QB];
    __shared__ float  redL[2][QB];

    int lin  = blockIdx.x;
    int qb   = lin >> 1, half = lin & 1;
    int b    = qb & 7;
    int q0   = (qb >> 3) * QB;
    int tid  = threadIdx.x;
    int w    = tid >> 6, lane = tid & 63;
    int rt   = w & 1, wc = w >> 1;
    int g    = lane >> 4, ln = lane & 15;

    long rowbase = (long)b * N_ + q0;
    const u16* Kbh = Kh + ((long)b * N_ + half * 1024) * DP;
    const u16* Kbl = Kl + ((long)b * N_ + half * 1024) * DP;

    short8 ah[4], al[4];
    {
        const u16* qh = Qh + (rowbase + rt * 16 + ln) * DP;
        const u16* ql = Ql + (rowbase + rt * 16 + ln) * DP;
        #pragma unroll
        for (int ks = 0; ks < 4; ++ks){
            ah[ks] = *(const short8*)(qh + ks * 32 + g * 8);
            al[ks] = *(const short8*)(ql + ks * 32 + g * 8);
        }
    }

    int mrow  = wc * 16 + ln;
    int swz   = ln & 7;
    int mybit = wc * 16 + ln;
    long bitbase[4];
    #pragma unroll
    for (int i = 0; i < 4; ++i)
        bitbase[i] = (rowbase + rt * 16 + g * 4 + i) * 64 + half * 32;

    int r0 = tid >> 4,          c0 = tid & 15;
    int slot0 = r0 * 16 + (c0 ^ (r0 & 7));
    int r1 = (tid + 256) >> 4,  c1 = tid & 15;
    int slot1 = r1 * 16 + (c1 ^ (r1 & 7));

    short8 kAh0, kAh1, kAl0, kAl1;
    short8 kBh0, kBh1, kBl0, kBl1;

    float mx[4], ls[4];
    #pragma unroll
    for (int i = 0; i < 4; ++i){ mx[i] = -1e30f; ls[i] = 0.f; }

    {   // prologue: direct-stage K0, prefetch K1/K2
        short8 h0 = *(const short8*)(Kbh + (long)tid * 8);
        short8 h1 = *(const short8*)(Kbh + (long)(tid + 256) * 8);
        short8 l0 = *(const short8*)(Kbl + (long)tid * 8);
        short8 l1 = *(const short8*)(Kbl + (long)(tid + 256) * 8);
        ISSUE_K2(kA, 1);
        ISSUE_K2(kB, 2);
        KsH[0][slot0] = h0; KsH[0][slot1] = h1;
        KsL[0][slot0] = l0; KsL[0][slot1] = l1;
        bar_lds();
    }
    for (int t = 0; t < NT2; t += 2){
        u32x2 wd[4];
        #pragma unroll
        for (int i = 0; i < 4; ++i) wd[i] = *(const u32x2*)(bits + bitbase[i] + t);

        #pragma unroll
        for (int sub = 0; sub < 2; ++sub){
            f32x4 s0 = {0.f,0.f,0.f,0.f}, s1 = s0, s2 = s0;
            __builtin_amdgcn_s_setprio(1);
            #pragma unroll
            for (int ks = 0; ks < 4; ++ks){
                int cu = (ks * 4 + g) ^ swz;
                short8 bh = KsH[sub][mrow * 16 + cu];
                short8 bl = KsL[sub][mrow * 16 + cu];
                s0 = mfma16(ah[ks], bh, s0);
                s1 = mfma16(al[ks], bh, s1);
                s2 = mfma16(ah[ks], bl, s2);
            }
            __builtin_amdgcn_s_setprio(0);
            f32x4 s = s0 + s1 + s2;
            #pragma unroll
            for (int i = 0; i < 4; ++i){
                float sv = ((wd[i][sub] >> mybit) & 1u) ? s[i] : -3.0e38f;
                if (__any(sv > mx[i])){
                    float nm = fmaxf(mx[i], sv);
                    ls[i] *= exp2f(mx[i] - nm);
                    mx[i] = nm;
                }
                ls[i] += exp2f(sv - mx[i]);
            }
            if (sub == 0){
                KsH[1][slot0] = kAh0; KsH[1][slot1] = kAh1;
                KsL[1][slot0] = kAl0; KsL[1][slot1] = kAl1;
                if (t + 3 < NT2) ISSUE_K2(kA, t + 3);
            } else {
                if (t + 2 < NT2){
                    KsH[0][slot0] = kBh0; KsH[0][slot1] = kBh1;
                    KsL[0][slot0] = kBl0; KsL[0][slot1] = kBl1;
                }
                if (t + 4 < NT2) ISSUE_K2(kB, t + 4);
            }
            bar_lds();
        }
    }

    // merge across the 16 ln lanes
    #pragma unroll
    for (int i = 0; i < 4; ++i){
        #pragma unroll
        for (int sft = 1; sft < 16; sft <<= 1){
            float om = __shfl_xor(mx[i], sft, 64);
            float ol = __shfl_xor(ls[i], sft, 64);
            float nm = fmaxf(mx[i], om);
            ls[i] = ls[i] * exp2f(mx[i] - nm) + ol * exp2f(om - nm);
            mx[i] = nm;
        }
    }
    if (ln == 0){
        #pragma unroll
        for (int i = 0; i < 4; ++i){
            redM[wc][rt * 16 + g * 4 + i] = mx[i];
            redL[wc][rt * 16 + g * 4 + i] = ls[i];
        }
    }
    __syncthreads();
    if (tid < QB){
        float m0_ = redM[0][tid], m1_ = redM[1][tid];
        float M  = fmaxf(m0_, m1_);
        float L  = redL[0][tid] * exp2f(m0_ - M) + redL[1][tid] * exp2f(m1_ - M);
        Mpart[(long)lin * QB + tid] = M;
        Lpart[(long)lin * QB + tid] = L;
    }
}

// ---------------------------------------------------------------------------
// Kernel 2b: pass B — S recompute + P + PV over ONE m-half.
// grid 1024, LDS 26.5 KB -> 4 blocks/CU. Single-buffered K/V (2 bars/tile),
// Ps stored bf16 (direct PV A-fragment). Output via f32 atomicAdd.
// ---------------------------------------------------------------------------
__global__ __launch_bounds__(256, 4)
void attnB_kernel(const u16* __restrict__ Qh, const u16* __restrict__ Ql,
                  const u16* __restrict__ Kh, const u16* __restrict__ Kl,
                  const u16* __restrict__ Vt, const u32* __restrict__ bits,
                  const float* __restrict__ Mpart, const float* __restrict__ Lpart,
                  float* __restrict__ outp, float* __restrict__ attnw){
    __shared__ short8 KsH1[512];       // 8 KB (32 rows x 16 units, swizzled)
    __shared__ short8 KsL1[512];
    __shared__ short8 Vs1[512];        // 8 KB (128 e x 4 units, swizzled)
    __shared__ u16    PsB[QB * MT];    // 2 KB P tile (bf16), [row][col]
    __shared__ float  smax[QB];
    __shared__ float  sinv[QB];

    int lin  = blockIdx.x;
    int qb   = lin >> 1, half = lin & 1;
    int b    = qb & 7;
    int q0   = (qb >> 3) * QB;
    int tid  = threadIdx.x;
    int w    = tid >> 6, lane = tid & 63;
    int rt   = w & 1, wc = w >> 1;
    int g    = lane >> 4, ln = lane & 15;

    long rowbase = (long)b * N_ + q0;
    const u16* Kbh = Kh + ((long)b * N_ + half * 1024) * DP;
    const u16* Kbl = Kl + ((long)b * N_ + half * 1024) * DP;
    const u16* Vb  = Vt + ((long)b * 64 + half * 32) * 4096;

    // merge the two (M,L) halves -> global softmax stats
    if (tid < QB){
        float m0 = Mpart[(long)qb * 64 + tid];
        float m1 = Mpart[(long)qb * 64 + 32 + tid];
        float M  = fmaxf(m0, m1);
        float L  = Lpart[(long)qb * 64 + tid] * exp2f(m0 - M)
                 + Lpart[(long)qb * 64 + 32 + tid] * exp2f(m1 - M);
        smax[tid] = M;
        sinv[tid] = 1.f / L;
    }
    __syncthreads();
    float Mr[4], Ir[4];
    #pragma unroll
    for (int i = 0; i < 4; ++i){
        Mr[i] = smax[rt * 16 + g * 4 + i];
        Ir[i] = sinv[rt * 16 + g * 4 + i];
    }

    short8 ah[4], al[4];
    {
        const u16* qh = Qh + (rowbase + rt * 16 + ln) * DP;
        const u16* ql = Ql + (rowbase + rt * 16 + ln) * DP;
        #pragma unroll
        for (int ks = 0; ks < 4; ++ks){
            ah[ks] = *(const short8*)(qh + ks * 32 + g * 8);
            al[ks] = *(const short8*)(ql + ks * 32 + g * 8);
        }
    }

    int mrow  = wc * 16 + ln;
    int swz   = ln & 7;
    int mybit = wc * 16 + ln;
    long bitbase[4];
    #pragma unroll
    for (int i = 0; i < 4; ++i)
        bitbase[i] = (rowbase + rt * 16 + g * 4 + i) * 64 + half * 32;

    int r0 = tid >> 4,          c0 = tid & 15;
    int slot0 = r0 * 16 + (c0 ^ (r0 & 7));
    int r1 = (tid + 256) >> 4,  c1 = tid & 15;
    int slot1 = r1 * 16 + (c1 ^ (r1 & 7));
    int e0 = tid >> 2,          m0i = tid & 3;
    int vslot0 = e0 * 4 + (m0i ^ ((e0 >> 1) & 3));
    int e1 = (tid + 256) >> 2;
    int vslot1 = e1 * 4 + (m0i ^ ((e1 >> 1) & 3));

    short8 kNh0, kNh1, kNl0, kNl1;   // K tile t+1 prefetch
    short8 vN0, vN1;                 // V tile t+1 prefetch

    f32x4 acc[4];
    #pragma unroll
    for (int e = 0; e < 4; ++e) acc[e] = (f32x4){0.f, 0.f, 0.f, 0.f};

    {   // prologue: direct-stage K0,V0; prefetch K1,V1
        short8 h0 = *(const short8*)(Kbh + (long)tid * 8);
        short8 h1 = *(const short8*)(Kbh + (long)(tid + 256) * 8);
        short8 l0 = *(const short8*)(Kbl + (long)tid * 8);
        short8 l1 = *(const short8*)(Kbl + (long)(tid + 256) * 8);
        short8 v0 = *(const short8*)(Vb + (long)tid * 8);
        short8 v1 = *(const short8*)(Vb + (long)(tid + 256) * 8);
        if (1 < NT2){
            long gb_ = (long)1 * MT * DP;
            kNh0 = *(const short8*)(Kbh + gb_ + (long)tid * 8);
            kNh1 = *(const short8*)(Kbh + gb_ + (long)(tid + 256) * 8);
            kNl0 = *(const short8*)(Kbl + gb_ + (long)tid * 8);
            kNl1 = *(const short8*)(Kbl + gb_ + (long)(tid + 256) * 8);
            vN0  = *(const short8*)(Vb + 4096 + (long)tid * 8);
            vN1  = *(const short8*)(Vb + 4096 + (long)(tid + 256) * 8);
        }
        KsH1[slot0] = h0; KsH1[slot1] = h1;
        KsL1[slot0] = l0; KsL1[slot1] = l1;
        Vs1[vslot0] = v0; Vs1[vslot1] = v1;
        bar_lds();
    }

    for (int t = 0; t < NT2; ++t){
        u32 wd[4];
        #pragma unroll
        for (int i = 0; i < 4; ++i) wd[i] = bits[bitbase[i] + t];

        // S recompute (3-chain split)
        f32x4 s0 = {0.f,0.f,0.f,0.f}, s1 = s0, s2 = s0;
        __builtin_amdgcn_s_setprio(1);
        #pragma unroll
        for (int ks = 0; ks < 4; ++ks){
            int cu = (ks * 4 + g) ^ swz;
            short8 bh = KsH1[mrow * 16 + cu];
            short8 bl = KsL1[mrow * 16 + cu];
            s0 = mfma16(ah[ks], bh, s0);
            s1 = mfma16(al[ks], bh, s1);
            s2 = mfma16(ah[ks], bl, s2);
        }
        __builtin_amdgcn_s_setprio(0);
        f32x4 s = s0 + s1 + s2;

        // normalized P -> bf16 LDS tile
        #pragma unroll
        for (int i = 0; i < 4; ++i){
            float p = ((wd[i] >> mybit) & 1u) ? exp2f(s[i] - Mr[i]) * Ir[i] : 0.f;
            int prow = rt * 16 + g * 4 + i;
            PsB[prow * MT + mybit] = f2bf(p);
        }
        bar_lds();   // bar1: P ready; all K reads done

        // coalesced attnw store (convert bf16 -> f32)
        {
            int row = tid >> 3, c4 = (tid & 7) * 4;
            u32 a = *(const u32*)&PsB[row * MT + c4];
            u32 bwd = *(const u32*)&PsB[row * MT + c4 + 2];
            f32x4 pv = { bf2f((u16)(a & 0xffff)),  bf2f((u16)(a >> 16)),
                         bf2f((u16)(bwd & 0xffff)), bf2f((u16)(bwd >> 16)) };
            *(f32x4*)(attnw + (rowbase + row) * N_ + half * 1024 + t * MT + c4) = pv;
        }
        // PV: A-fragment directly from bf16 tile
        {
            short8 pa = *(const short8*)&PsB[(rt * 16 + ln) * MT + g * 8];
            __builtin_amdgcn_s_setprio(1);
            #pragma unroll
            for (int ef = 0; ef < 4; ++ef){
                int e = wc * 64 + ef * 16 + ln;
                short8 vb = Vs1[e * 4 + (g ^ ((e >> 1) & 3))];
                acc[ef] = mfma16(pa, vb, acc[ef]);
            }
            __builtin_amdgcn_s_setprio(0);
        }
        if (t + 1 < NT2){
            KsH1[slot0] = kNh0; KsH1[slot1] = kNh1;
            KsL1[slot0] = kNl0; KsL1[slot1] = kNl1;
            if (t + 2 < NT2){
                long gb_ = (long)(t + 2) * MT * DP;
                kNh0 = *(const short8*)(Kbh + gb_ + (long)tid * 8);
                kNh1 = *(const short8*)(Kbh + gb_ + (long)(tid + 256) * 8);
                kNl0 = *(const short8*)(Kbl + gb_ + (long)tid * 8);
                kNl1 = *(const short8*)(Kbl + gb_ + (long)(tid + 256) * 8);
            }
        }
        bar_lds();   // bar2: PV/attnw reads done; K write done
        if (t + 1 < NT2){
            Vs1[vslot0] = vN0; Vs1[vslot1] = vN1;
            if (t + 2 < NT2){
                const u16* vt_ = Vb + (long)(t + 2) * 4096;
                vN0 = *(const short8*)(vt_ + (long)tid * 8);
                vN1 = *(const short8*)(vt_ + (long)(tid + 256) * 8);
            }
        }
    }

    // ---- output: accumulate partial O across the two m-halves ----
    #pragma unroll
    for (int ef = 0; ef < 4; ++ef){
        #pragma unroll
        for (int i = 0; i < 4; ++i){
            int col = wc * 64 + ef * 16 + ln;
            if (col < D_)
                atomicAdd(outp + (rowbase + rt * 16 + g * 4 + i) * D_ + col,
                          acc[ef][i]);
        }
    }
}

// ---------------------------------------------------------------------------
extern "C" void kernel_launch(void* const* d_in, const int* in_sizes, int n_in,
                              void* d_out, int out_size, void* d_ws, size_t ws_size,
                              hipStream_t stream){
    const float* x1   = (const float*)d_in[0];
    const float* x2   = (const float*)d_in[1];
    const int*   mask = (const int*)d_in[2];
    const float* Wq   = (const float*)d_in[3];
    const float* Wk   = (const float*)d_in[4];
    const float* Wv   = (const float*)d_in[5];

    float* outp  = (float*)d_out;
    float* attnw = outp + (size_t)B_ * N_ * D_;   // outputs concatenated flat

    const size_t TEN = (size_t)B_ * N_ * DP;      // 2,097,152
    u32* bits = (u32*)d_ws;                       // 4 MB
    u16* Qh   = (u16*)(bits + (size_t)B_ * N_ * 64);
    u16* Ql   = Qh + TEN;
    u16* Kh   = Ql + TEN;
    u16* Kl   = Kh + TEN;
    u16* Vt   = Kl + TEN;                         // tile-major [B][64][128][32]
    u16* Wth  = Vt + TEN;
    u16* Wtl  = Wth + (size_t)3 * DP * DP;
    float* Mpart = (float*)(Wtl + (size_t)3 * DP * DP);   // 1024*32 f32
    float* Lpart = Mpart + 1024 * QB;

    // zero O for the cross-half atomic accumulation
    hipMemsetAsync(outp, 0, (size_t)B_ * N_ * D_ * sizeof(float), stream);

    hipLaunchKernelGGL(wprep, dim3(3), dim3(256), 0, stream, Wq, Wk, Wv, Wth, Wtl);
    hipLaunchKernelGGL(projmask_kernel, dim3(768 + 4096), dim3(256), 0, stream,
                       x1, x2, mask, Wth, Wtl, Qh, Ql, Kh, Kl, Vt, bits);
    hipLaunchKernelGGL(attnA_kernel, dim3(1024), dim3(256), 0, stream,
                       Qh, Ql, Kh, Kl, bits, Mpart, Lpart);
    hipLaunchKernelGGL(attnB_kernel, dim3(1024), dim3(256), 0, stream,
                       Qh, Ql, Kh, Kl, Vt, bits, Mpart, Lpart, outp, attnw);
}

// Round 11
// 253.067 us; speedup vs baseline: 1.1337x; 1.0668x over previous
//
#include <hip/hip_runtime.h>
#include <stdint.h>

#define B_ 8
#define N_ 2048
#define D_ 120
#define DP 128          // D padded to 128 (k-dim of MFMA)
#define QB 32           // q rows per attention block
#define MT 32           // m-tile (k/v rows per step)
#define NT (N_ / MT)    // 64 steps

typedef __attribute__((ext_vector_type(8))) short short8;
typedef __attribute__((ext_vector_type(4))) float f32x4;
typedef __attribute__((ext_vector_type(4))) float float4v;
typedef __attribute__((ext_vector_type(2))) unsigned int u32x2;
typedef unsigned short u16;
typedef unsigned int u32;

__device__ __forceinline__ u16 f2bf(float f){
    union { float f; uint32_t u; } v; v.f = f;
    uint32_t u = v.u;
    return (u16)((u + 0x7fffu + ((u >> 16) & 1u)) >> 16);
}
__device__ __forceinline__ float bf2f(u16 h){
    union { uint32_t u; float f; } v; v.u = ((uint32_t)h) << 16; return v.f;
}
__device__ __forceinline__ f32x4 mfma16(short8 a, short8 b, f32x4 c){
    return __builtin_amdgcn_mfma_f32_16x16x32_bf16(a, b, c, 0, 0, 0);
}
// LDS-only barrier: drain LDS ops, do NOT drain vmcnt.
__device__ __forceinline__ void bar_lds(){
    asm volatile("s_waitcnt lgkmcnt(0)\n\ts_barrier" ::: "memory");
}

// ---------------------------------------------------------------------------
// Kernel 0: transpose + split weights (bf16 hi/lo), zero-padded to 128x128.
// Wq scale = log2(e)/sqrt(120): scores live in the exp2 domain.
// ---------------------------------------------------------------------------
__global__ void wprep(const float* __restrict__ Wq, const float* __restrict__ Wk,
                      const float* __restrict__ Wv,
                      u16* __restrict__ Wth, u16* __restrict__ Wtl){
    int p = blockIdx.x;
    const float* W = (p == 0) ? Wq : (p == 1 ? Wk : Wv);
    float scale = (p == 0) ? 0.13169943749474f : 1.0f;   // log2e/sqrt(120)
    for (int idx = threadIdx.x; idx < DP * DP; idx += blockDim.x){
        int c = idx & (DP - 1);
        int d = idx >> 7;
        float w = (c < D_ && d < D_) ? W[d * D_ + c] * scale : 0.f;
        u16 hi = f2bf(w);
        Wth[p * DP * DP + c * DP + d] = hi;
        Wtl[p * DP * DP + c * DP + d] = f2bf(w - bf2f(hi));
    }
}

// ---------------------------------------------------------------------------
// Kernel 0b: mask -> bitmask (2048 int32 -> 64 u32 per row), coalesced.
// Separate kernel (no big static LDS -> full occupancy, BW-bound).
// ---------------------------------------------------------------------------
__global__ __launch_bounds__(256)
void maskprep(const int* __restrict__ mask, u32* __restrict__ bits){
    int wid  = (blockIdx.x * 256 + threadIdx.x) >> 6;
    int lane = threadIdx.x & 63;
    long base = (long)wid * N_;
    u32 myw = 0;
    #pragma unroll
    for (int it = 0; it < 32; ++it){
        int v = mask[base + it * 64 + lane];
        unsigned long long bb = __ballot(v != 0);
        if ((lane >> 1) == it)
            myw = (lane & 1) ? (u32)(bb >> 32) : (u32)bb;
    }
    bits[((long)wid << 6) + lane] = myw;
}

// ---------------------------------------------------------------------------
// Kernel 1: projections. W (hi+lo) staged in swizzled LDS; V written
// tile-major [b][t][e][32] via LDS transpose (coalesced stores).
// ---------------------------------------------------------------------------
__global__ __launch_bounds__(256, 2)
void proj_kernel(const float* __restrict__ x1, const float* __restrict__ x2,
                 const u16* __restrict__ Wth, const u16* __restrict__ Wtl,
                 u16* __restrict__ Qh, u16* __restrict__ Ql,
                 u16* __restrict__ Kh, u16* __restrict__ Kl,
                 u16* __restrict__ Vt){
    __shared__ short8 smem8[4096];          // 64 KB: WH[2048] | WL[2048]
    short8* WHs = smem8;
    short8* WLs = smem8 + 2048;
    u16* vtl = (u16*)smem8;                 // reused after compute: [128][64]

    int p    = blockIdx.y;
    const float* x = (p == 0) ? x1 : x2;
    int tid  = threadIdx.x;
    int wave = tid >> 6, lane = tid & 63;
    int g = lane >> 4, ln = lane & 15;
    long arow = (long)blockIdx.x * 64 + wave * 16 + ln;

    const u16* wh = Wth + p * DP * DP;
    const u16* wl = Wtl + p * DP * DP;
    #pragma unroll
    for (int j = 0; j < 8; ++j){
        int u = tid + j * 256;
        int row = u >> 4, cu = u & 15;
        int slot = row * 16 + (cu ^ (row & 7));
        WHs[slot] = *(const short8*)(wh + (long)u * 8);
        WLs[slot] = *(const short8*)(wl + (long)u * 8);
    }

    short8 ah[4], al[4];
    #pragma unroll
    for (int ks = 0; ks < 4; ++ks){
        int d0 = ks * 32 + g * 8;
        float xv[8];
        if (d0 < D_){
            float4v v0 = *(const float4v*)(x + arow * D_ + d0);
            float4v v1 = *(const float4v*)(x + arow * D_ + d0 + 4);
            xv[0]=v0[0]; xv[1]=v0[1]; xv[2]=v0[2]; xv[3]=v0[3];
            xv[4]=v1[0]; xv[5]=v1[1]; xv[6]=v1[2]; xv[7]=v1[3];
        } else {
            #pragma unroll
            for (int j = 0; j < 8; ++j) xv[j] = 0.f;
        }
        short8 h, l;
        #pragma unroll
        for (int j = 0; j < 8; ++j){
            u16 hb = f2bf(xv[j]);
            h[j] = (short)hb;
            l[j] = (short)f2bf(xv[j] - bf2f(hb));
        }
        ah[ks] = h; al[ks] = l;
    }
    __syncthreads();

    f32x4 acc[8];
    #pragma unroll
    for (int cf = 0; cf < 8; ++cf){
        f32x4 s0 = {0.f,0.f,0.f,0.f}, s1 = {0.f,0.f,0.f,0.f}, s2 = {0.f,0.f,0.f,0.f};
        int rbase = (cf * 16 + ln) * 16;
        #pragma unroll
        for (int ks = 0; ks < 4; ++ks){
            int cu = (ks * 4 + g) ^ (ln & 7);
            short8 bh = WHs[rbase + cu];
            short8 bl = WLs[rbase + cu];
            s0 = mfma16(ah[ks], bh, s0);
            s1 = mfma16(al[ks], bh, s1);
            s2 = mfma16(ah[ks], bl, s2);
        }
        acc[cf] = s0 + s1 + s2;
    }

    if (p < 2){
        #pragma unroll
        for (int cf = 0; cf < 8; ++cf){
            #pragma unroll
            for (int i = 0; i < 4; ++i){
                long orow = (long)blockIdx.x * 64 + wave * 16 + g * 4 + i;
                int  c    = cf * 16 + ln;
                float v   = acc[cf][i];
                u16 hb = f2bf(v);
                if (p == 0){
                    Qh[orow * DP + c] = hb;
                    Ql[orow * DP + c] = f2bf(v - bf2f(hb));
                } else {
                    Kh[orow * DP + c] = hb;
                    Kl[orow * DP + c] = f2bf(v - bf2f(hb));
                }
            }
        }
    } else {
        __syncthreads();
        #pragma unroll
        for (int cf = 0; cf < 8; ++cf){
            #pragma unroll
            for (int i = 0; i < 4; ++i){
                int c    = cf * 16 + ln;
                int lrow = wave * 16 + g * 4 + i;
                vtl[c * 64 + lrow] = f2bf(acc[cf][i]);
            }
        }
        __syncthreads();
        int c = tid >> 1, half = tid & 1;
        long n0 = ((long)blockIdx.x * 64) & 2047;
        long bb = ((long)blockIdx.x * 64) >> 11;
        long tbase = ((bb * 64 + (n0 >> 5) + half) * 128 + c) * 32;
        #pragma unroll
        for (int j = 0; j < 4; ++j){
            short8 v = *(const short8*)&vtl[c * 64 + half * 32 + j * 8];
            *(short8*)(Vt + tbase + j * 8) = v;
        }
    }
}

// ---------------------------------------------------------------------------
// Kernel 2: fused flash attention (R8 structure) + bf16 P tile (54 KB LDS ->
// 3 blocks/CU) + exp2-domain softmax.
// ---------------------------------------------------------------------------
#define ISSUE_K(P, T) do{ long gb_ = (long)(T) * MT * DP;                         \
    P##h0 = *(const short8*)(Kbh + gb_ + (long)tid * 8);                          \
    P##h1 = *(const short8*)(Kbh + gb_ + (long)(tid + 256) * 8);                  \
    P##l0 = *(const short8*)(Kbl + gb_ + (long)tid * 8);                          \
    P##l1 = *(const short8*)(Kbl + gb_ + (long)(tid + 256) * 8); }while(0)

#define WRITE_K(BUF, P) do{                                                       \
    KsH[BUF][slot0] = P##h0; KsH[BUF][slot1] = P##h1;                             \
    KsL[BUF][slot0] = P##l0; KsL[BUF][slot1] = P##l1; }while(0)

#define ISSUE_V(P, T) do{ const u16* vt_ = Vb + (long)(T) * 4096;                 \
    P##0 = *(const short8*)(vt_ + (long)tid * 8);                                 \
    P##1 = *(const short8*)(vt_ + (long)(tid + 256) * 8); }while(0)

#define WRITE_V(BUF, P) do{ Vs[BUF][vslot0] = P##0; Vs[BUF][vslot1] = P##1; }while(0)

#define COMPUTE_S(CB, SD) do{                                                     \
    f32x4 s0_ = {0.f,0.f,0.f,0.f}, s1_ = s0_, s2_ = s0_;                          \
    __builtin_amdgcn_s_setprio(1);                                                \
    _Pragma("unroll") for (int ks_ = 0; ks_ < 4; ++ks_){                          \
        int cu_ = (ks_ * 4 + g) ^ swz;                                            \
        short8 bh_ = KsH[CB][mrow * 16 + cu_];                                    \
        short8 bl_ = KsL[CB][mrow * 16 + cu_];                                    \
        s0_ = mfma16(ah[ks_], bh_, s0_);                                          \
        s1_ = mfma16(al[ks_], bh_, s1_);                                          \
        s2_ = mfma16(ah[ks_], bl_, s2_); }                                        \
    __builtin_amdgcn_s_setprio(0);                                                \
    SD = s0_ + s1_ + s2_; }while(0)

#define ONLINE(W0, W1, W2, W3, S) do{ u32 ww_[4] = {W0, W1, W2, W3};              \
    _Pragma("unroll") for (int i = 0; i < 4; ++i){                                \
        float sv_ = ((ww_[i] >> mybit) & 1u) ? (S)[i] : -3.0e38f;                 \
        if (__any(sv_ > mx[i])){                                                  \
            float nm_ = fmaxf(mx[i], sv_);                                        \
            ls[i] *= exp2f(mx[i] - nm_); mx[i] = nm_;                             \
        }                                                                         \
        ls[i] += exp2f(sv_ - mx[i]); } }while(0)

#define PNORM(W0, W1, W2, W3, S, PD) do{ u32 ww_[4] = {W0, W1, W2, W3};           \
    _Pragma("unroll") for (int i = 0; i < 4; ++i)                                 \
        PD[i] = ((ww_[i] >> mybit) & 1u) ? exp2f((S)[i] - Mr[i]) * Ir[i] : 0.f;   \
    }while(0)

// P tile bf16, swizzle col ^ ((row&3)<<3)
#define PWRITE(PB, PD) do{ _Pragma("unroll") for (int i = 0; i < 4; ++i){         \
    int prow_ = rt * 16 + g * 4 + i;                                              \
    PsB[PB][prow_ * 32 + (mybit ^ ((prow_ & 3) << 3))] = f2bf(PD[i]); } }while(0)

#define PV_STEP(PB, VBUF, TPREV) do{                                              \
    int row_ = tid >> 3, c4_ = (tid & 7) * 4;                                     \
    int slt_ = row_ * 32 + (c4_ ^ ((row_ & 3) << 3));                             \
    u32 wa_ = *(const u32*)&PsB[PB][slt_];                                        \
    u32 wb_ = *(const u32*)&PsB[PB][slt_ + 2];                                    \
    f32x4 pv_ = { bf2f((u16)(wa_ & 0xffff)), bf2f((u16)(wa_ >> 16)),              \
                  bf2f((u16)(wb_ & 0xffff)), bf2f((u16)(wb_ >> 16)) };            \
    *(f32x4*)(attnw + (rowbase + row_) * N_ + (long)(TPREV) * MT + c4_) = pv_;    \
    int prow_ = rt * 16 + ln;                                                     \
    short8 pa_ = *(const short8*)&PsB[PB][prow_ * 32 + ((g * 8) ^ ((prow_ & 3) << 3))]; \
    __builtin_amdgcn_s_setprio(1);                                                \
    _Pragma("unroll") for (int ef_ = 0; ef_ < 4; ++ef_){                          \
        int e_ = wc * 64 + ef_ * 16 + ln;                                         \
        short8 vb_ = Vs[VBUF][e_ * 4 + (g ^ ((e_ >> 1) & 3))];                    \
        acc[ef_] = mfma16(pa_, vb_, acc[ef_]); }                                  \
    __builtin_amdgcn_s_setprio(0); }while(0)

__global__ __launch_bounds__(256, 3)
void attn_kernel(const u16* __restrict__ Qh, const u16* __restrict__ Ql,
                 const u16* __restrict__ Kh, const u16* __restrict__ Kl,
                 const u16* __restrict__ Vt, const u32* __restrict__ bits,
                 float* __restrict__ outp, float* __restrict__ attnw){
    __shared__ short8 KsH[2][512];     // 16 KB [buf][32 rows x 16 units] swz
    __shared__ short8 KsL[2][512];     // 16 KB
    __shared__ short8 Vs [2][512];     // 16 KB [buf][128 e x 4 units] swz
    __shared__ u16    PsB[2][QB * MT]; // 4 KB P tile bf16, col^((row&3)<<3)
    __shared__ float  redM[2][QB];
    __shared__ float  redL[2][QB];
    __shared__ float  smax[QB];
    __shared__ float  sinv[QB];

    int lin = blockIdx.x;
    int b   = lin & 7;                  // batch == XCD (round-robin dispatch)
    int q0  = (lin >> 3) * QB;
    int tid = threadIdx.x;
    int w   = tid >> 6, lane = tid & 63;
    int rt  = w & 1, wc = w >> 1;
    int g   = lane >> 4, ln = lane & 15;

    long rowbase = (long)b * N_ + q0;
    const u16* Kbh = Kh + (long)b * N_ * DP;
    const u16* Kbl = Kl + (long)b * N_ * DP;
    const u16* Vb  = Vt + ((long)b * 64) * 4096;   // tile-major: +t*4096

    // Q A-fragments
    short8 ah[4], al[4];
    {
        const u16* qh = Qh + (rowbase + rt * 16 + ln) * DP;
        const u16* ql = Ql + (rowbase + rt * 16 + ln) * DP;
        #pragma unroll
        for (int ks = 0; ks < 4; ++ks){
            ah[ks] = *(const short8*)(qh + ks * 32 + g * 8);
            al[ks] = *(const short8*)(ql + ks * 32 + g * 8);
        }
    }

    int mrow  = wc * 16 + ln;
    int swz   = ln & 7;
    int mybit = wc * 16 + ln;
    long bitbase[4];
    #pragma unroll
    for (int i = 0; i < 4; ++i) bitbase[i] = (rowbase + rt * 16 + g * 4 + i) * 64;

    int r0 = tid >> 4,          c0 = tid & 15;
    int slot0 = r0 * 16 + (c0 ^ (r0 & 7));
    int r1 = (tid + 256) >> 4,  c1 = tid & 15;
    int slot1 = r1 * 16 + (c1 ^ (r1 & 7));
    int e0 = tid >> 2,          m0 = tid & 3;
    int vslot0 = e0 * 4 + (m0 ^ ((e0 >> 1) & 3));
    int e1 = (tid + 256) >> 2;
    int vslot1 = e1 * 4 + (m0 ^ ((e1 >> 1) & 3));

    // prefetch register sets (statically named — rule #20)
    short8 kAh0, kAh1, kAl0, kAl1;
    short8 kBh0, kBh1, kBl0, kBl1;
    short8 vA0, vA1, vB0, vB1;

    // ================= PASS A: max + sum (lazy online) =================
    float mx[4], ls[4];
    #pragma unroll
    for (int i = 0; i < 4; ++i){ mx[i] = -1e30f; ls[i] = 0.f; }

    {   // prologue: direct-stage K0, prefetch K1/K2
        short8 h0 = *(const short8*)(Kbh + (long)tid * 8);
        short8 h1 = *(const short8*)(Kbh + (long)(tid + 256) * 8);
        short8 l0 = *(const short8*)(Kbl + (long)tid * 8);
        short8 l1 = *(const short8*)(Kbl + (long)(tid + 256) * 8);
        ISSUE_K(kA, 1);
        ISSUE_K(kB, 2);
        KsH[0][slot0] = h0; KsH[0][slot1] = h1;
        KsL[0][slot0] = l0; KsL[0][slot1] = l1;
        bar_lds();
    }
    for (int t = 0; t < NT; t += 2){
        u32x2 wd[4];
        #pragma unroll
        for (int i = 0; i < 4; ++i) wd[i] = *(const u32x2*)(bits + bitbase[i] + t);

        f32x4 s;
        COMPUTE_S(0, s);
        ONLINE(wd[0][0], wd[1][0], wd[2][0], wd[3][0], s);
        WRITE_K(1, kA);                       // tile t+1 (issued >=2 iters ago)
        if (t + 3 < NT) ISSUE_K(kA, t + 3);
        bar_lds();

        COMPUTE_S(1, s);
        ONLINE(wd[0][1], wd[1][1], wd[2][1], wd[3][1], s);
        if (t + 2 < NT) WRITE_K(0, kB);       // tile t+2
        if (t + 4 < NT) ISSUE_K(kB, t + 4);
        bar_lds();
    }

    // merge across the 16 ln lanes
    #pragma unroll
    for (int i = 0; i < 4; ++i){
        #pragma unroll
        for (int sft = 1; sft < 16; sft <<= 1){
            float om = __shfl_xor(mx[i], sft, 64);
            float ol = __shfl_xor(ls[i], sft, 64);
            float nm = fmaxf(mx[i], om);
            ls[i] = ls[i] * exp2f(mx[i] - nm) + ol * exp2f(om - nm);
            mx[i] = nm;
        }
    }
    if (ln == 0){
        #pragma unroll
        for (int i = 0; i < 4; ++i){
            redM[wc][rt * 16 + g * 4 + i] = mx[i];
            redL[wc][rt * 16 + g * 4 + i] = ls[i];
        }
    }
    __syncthreads();
    if (tid < QB){
        float m0_ = redM[0][tid], m1_ = redM[1][tid];
        float M  = fmaxf(m0_, m1_);
        float L  = redL[0][tid] * exp2f(m0_ - M) + redL[1][tid] * exp2f(m1_ - M);
        smax[tid] = M;
        sinv[tid] = 1.f / L;
    }
    __syncthreads();
    float Mr[4], Ir[4];
    #pragma unroll
    for (int i = 0; i < 4; ++i){
        Mr[i] = smax[rt * 16 + g * 4 + i];
        Ir[i] = sinv[rt * 16 + g * 4 + i];
    }

    // ================= PASS B: pipelined P store + PV =================
    f32x4 acc[4];
    #pragma unroll
    for (int e = 0; e < 4; ++e) acc[e] = (f32x4){0.f, 0.f, 0.f, 0.f};

    {   // prologue: restage K0; prefetch K1/K2 and V0/V1
        short8 h0 = *(const short8*)(Kbh + (long)tid * 8);
        short8 h1 = *(const short8*)(Kbh + (long)(tid + 256) * 8);
        short8 l0 = *(const short8*)(Kbl + (long)tid * 8);
        short8 l1 = *(const short8*)(Kbl + (long)(tid + 256) * 8);
        ISSUE_K(kA, 1);
        ISSUE_K(kB, 2);
        ISSUE_V(vA, 0);
        ISSUE_V(vB, 1);
        KsH[0][slot0] = h0; KsH[0][slot1] = h1;
        KsL[0][slot0] = l0; KsL[0][slot1] = l1;
        bar_lds();
    }
    for (int t = 0; t < NT; t += 2){
        u32x2 wd[4];
        #pragma unroll
        for (int i = 0; i < 4; ++i) wd[i] = *(const u32x2*)(bits + bitbase[i] + t);

        // even sub-iter: tile t (Ks[0])
        f32x4 s;
        COMPUTE_S(0, s);
        float pe[4];
        PNORM(wd[0][0], wd[1][0], wd[2][0], wd[3][0], s, pe);
        if (t > 0) PV_STEP(1, 1, t - 1);      // attnw + PV for tile t-1
        PWRITE(0, pe);                        // P tile t
        WRITE_K(1, kA);                       // K tile t+1
        if (t + 3 < NT) ISSUE_K(kA, t + 3);
        WRITE_V(0, vA);                       // V tile t
        if (t + 2 < NT) ISSUE_V(vA, t + 2);
        bar_lds();

        // odd sub-iter: tile t+1 (Ks[1])
        COMPUTE_S(1, s);
        float po[4];
        PNORM(wd[0][1], wd[1][1], wd[2][1], wd[3][1], s, po);
        PV_STEP(0, 0, t);                     // attnw + PV for tile t
        PWRITE(1, po);                        // P tile t+1
        if (t + 2 < NT) WRITE_K(0, kB);       // K tile t+2
        if (t + 4 < NT) ISSUE_K(kB, t + 4);
        WRITE_V(1, vB);                       // V tile t+1
        if (t + 3 < NT) ISSUE_V(vB, t + 3);
        bar_lds();
    }
    // epilogue: tile NT-1 (odd -> Ps[1], Vs[1])
    PV_STEP(1, 1, NT - 1);

    // ---- output store ----
    #pragma unroll
    for (int ef = 0; ef < 4; ++ef){
        #pragma unroll
        for (int i = 0; i < 4; ++i){
            int col = wc * 64 + ef * 16 + ln;
            if (col < D_)
                outp[(rowbase + rt * 16 + g * 4 + i) * D_ + col] = acc[ef][i];
        }
    }
}

// ---------------------------------------------------------------------------
extern "C" void kernel_launch(void* const* d_in, const int* in_sizes, int n_in,
                              void* d_out, int out_size, void* d_ws, size_t ws_size,
                              hipStream_t stream){
    const float* x1   = (const float*)d_in[0];
    const float* x2   = (const float*)d_in[1];
    const int*   mask = (const int*)d_in[2];
    const float* Wq   = (const float*)d_in[3];
    const float* Wk   = (const float*)d_in[4];
    const float* Wv   = (const float*)d_in[5];

    float* outp  = (float*)d_out;
    float* attnw = outp + (size_t)B_ * N_ * D_;   // outputs concatenated flat

    const size_t TEN = (size_t)B_ * N_ * DP;      // 2,097,152
    u32* bits = (u32*)d_ws;                       // B*N*64 u32 = 4 MB
    u16* Qh   = (u16*)(bits + (size_t)B_ * N_ * 64);
    u16* Ql   = Qh + TEN;
    u16* Kh   = Ql + TEN;
    u16* Kl   = Kh + TEN;
    u16* Vt   = Kl + TEN;                         // tile-major [B][64][128][32]
    u16* Wth  = Vt + TEN;
    u16* Wtl  = Wth + (size_t)3 * DP * DP;

    hipLaunchKernelGGL(wprep, dim3(3), dim3(256), 0, stream, Wq, Wk, Wv, Wth, Wtl);
    hipLaunchKernelGGL(maskprep, dim3((B_ * N_) / 4), dim3(256), 0, stream, mask, bits);
    hipLaunchKernelGGL(proj_kernel, dim3((B_ * N_) / 64, 3), dim3(256), 0, stream,
                       x1, x2, Wth, Wtl, Qh, Ql, Kh, Kl, Vt);
    hipLaunchKernelGGL(attn_kernel, dim3((B_ * N_) / QB), dim3(256), 0, stream,
                       Qh, Ql, Kh, Kl, Vt, bits, outp, attnw);
}